// Round 1
// baseline (237.978 us; speedup 1.0000x reference)
//
#include <hip/hip_runtime.h>

// Fused Conv3d(3->16,k3,valid) + bias + /2 + MaxPool3d(2) + GlobalAvgPool + bias + channel-sum
// N=32, Cin=3, D=32,H=64,W=64 -> conv (30,62,62) -> pool (15,31,31) -> out (32)
//
// out[n] = sum_c mean_windows( max_window(conv_c) ) / 2 + sum_c( conv_bias_c/2 + bias_c )
//
// Block = one (n, pd, 16x16 pooled hw-tile). Thread = one 2x2x2 pooled window.

#define TPH 16
#define TPW 16

__global__ __launch_bounds__(256, 2) void conv_pool_kernel(
    const float* __restrict__ x, const float* __restrict__ wgt,
    float* __restrict__ ws)
{
  // input tile: [ci][4 d][34 h][36 w-padded]  = 58,752 B
  __shared__ __align__(16) float xs[3*4*34*36];
  // weights: [c][ci][28 (27 used)] = 5,376 B, each (c,ci) chunk 16B-aligned
  __shared__ __align__(16) float wlds[16*3*28];
  __shared__ float wsum[4];

  const int tid = threadIdx.x;
  const int tile = blockIdx.x;            // 0..3 : pht = tile>>1, pwt = tile&1
  const int pht = tile >> 1, pwt = tile & 1;
  const int pd  = blockIdx.y;             // 0..14
  const int n   = blockIdx.z;             // 0..31

  // ---- stage weights: global [c][ci][kd][kh][kw] -> wlds[(c*3+ci)*28 + k]
  for (int i = tid; i < 16*81; i += 256) {
    int c = i / 81, r = i % 81;
    int ci = r / 27, k = r % 27;
    wlds[(c*3 + ci)*28 + k] = wgt[i];
  }

  // ---- stage input tile (guarded halo; h/w >= 64 -> 0, never used by valid threads)
  const int H0 = 32*pht, W0 = 32*pwt, D0 = 2*pd;
  const float* xn = x + (size_t)n * (3*32*64*64);
  for (int i = tid; i < 3*4*34*34; i += 256) {
    int wq = i % 34; int t = i / 34;
    int hq = t % 34; t /= 34;
    int dq = t & 3;  int ci = t >> 2;
    int gh = H0 + hq, gw = W0 + wq;
    float v = 0.f;
    if (gh < 64 && gw < 64)
      v = xn[((ci*32 + (D0 + dq))*64 + gh)*64 + gw];
    xs[((ci*4 + dq)*34 + hq)*36 + wq] = v;
  }
  __syncthreads();

  const int ty = tid >> 4, tx = tid & 15;
  const int ph = pht*TPH + ty, pw = pwt*TPW + tx;
  const bool valid = (ph < 31) && (pw < 31);

  float S = 0.f;
  #pragma unroll 1
  for (int c = 0; c < 16; ++c) {
    float acc[8];
    #pragma unroll
    for (int i = 0; i < 8; ++i) acc[i] = 0.f;

    #pragma unroll
    for (int ci = 0; ci < 3; ++ci) {
      // weights for (c,ci) into registers (contiguous, vectorizable LDS reads)
      float wr[27];
      const int wb = (c*3 + ci)*28;
      #pragma unroll
      for (int k = 0; k < 27; ++k) wr[k] = wlds[wb + k];

      #pragma unroll
      for (int dq = 0; dq < 4; ++dq) {
        // 4x4 (h,w) register patch for this input-depth slice
        float xr[16];
        const int xb = ((ci*4 + dq)*34 + 2*ty)*36 + 2*tx;
        #pragma unroll
        for (int r = 0; r < 4; ++r)
          #pragma unroll
          for (int q = 0; q < 4; ++q)
            xr[r*4 + q] = xs[xb + r*36 + q];

        #pragma unroll
        for (int dd = 0; dd < 2; ++dd) {
          const int kd = dq - dd;
          if (kd < 0 || kd > 2) continue;
          #pragma unroll
          for (int r = 0; r < 4; ++r) {
            #pragma unroll
            for (int dh = 0; dh < 2; ++dh) {
              const int kh = r - dh;
              if (kh < 0 || kh > 2) continue;
              #pragma unroll
              for (int kw = 0; kw < 3; ++kw)
                #pragma unroll
                for (int dw = 0; dw < 2; ++dw)
                  acc[dd*4 + dh*2 + dw] +=
                      wr[(kd*3 + kh)*3 + kw] * xr[r*4 + kw + dw];
            }
          }
        }
      }
    }
    // maxpool over the 2x2x2 window, accumulate over channels
    float m01 = fmaxf(acc[0], acc[1]);
    float m23 = fmaxf(acc[2], acc[3]);
    float m45 = fmaxf(acc[4], acc[5]);
    float m67 = fmaxf(acc[6], acc[7]);
    S += fmaxf(fmaxf(m01, m23), fmaxf(m45, m67));
  }
  if (!valid) S = 0.f;

  // deterministic block reduction
  #pragma unroll
  for (int off = 32; off > 0; off >>= 1) S += __shfl_down(S, off, 64);
  if ((tid & 63) == 0) wsum[tid >> 6] = S;
  __syncthreads();
  if (tid == 0) {
    float tot = wsum[0] + wsum[1] + wsum[2] + wsum[3];
    ws[n*64 + (pd*4 + tile)] = tot;   // 60 slots per n, all written every launch
  }
}

__global__ void finalize_kernel(const float* __restrict__ ws,
                                const float* __restrict__ cb,
                                const float* __restrict__ bias,
                                float* __restrict__ out)
{
  int n = threadIdx.x;
  if (n >= 32) return;
  float tot = 0.f;
  #pragma unroll 1
  for (int s = 0; s < 60; ++s) tot += ws[n*64 + s];
  float C = 0.f;
  #pragma unroll 1
  for (int c = 0; c < 16; ++c) C += cb[c]*0.5f + bias[c];
  out[n] = tot * (1.0f/(2.0f*14415.0f)) + C;
}

extern "C" void kernel_launch(void* const* d_in, const int* in_sizes, int n_in,
                              void* d_out, int out_size, void* d_ws, size_t ws_size,
                              hipStream_t stream) {
  (void)in_sizes; (void)n_in; (void)out_size; (void)ws_size;
  const float* x    = (const float*)d_in[0];
  const float* wgt  = (const float*)d_in[1];
  const float* cb   = (const float*)d_in[2];
  const float* bias = (const float*)d_in[3];
  float* out = (float*)d_out;
  float* ws  = (float*)d_ws;     // needs 32*64*4 = 8 KB

  dim3 grid(4, 15, 32);          // (hw-tile, pd, n) = 1920 blocks
  conv_pool_kernel<<<grid, 256, 0, stream>>>(x, wgt, ws);
  finalize_kernel<<<1, 64, 0, stream>>>(ws, cb, bias, out);
}

// Round 2
// 236.734 us; speedup vs baseline: 1.0053x; 1.0053x over previous
//
#include <hip/hip_runtime.h>

// Fused Conv3d(3->16,k3,valid) + bias + /2 + MaxPool3d(2) + GlobalAvgPool + bias + channel-sum
// N=32, Cin=3, D=32,H=64,W=64 -> conv (30,62,62) -> pool (15,31,31) -> out (32)
//
// out[n] = (1/(2*14415)) * sum_{c,windows} max_window(conv_c)  +  sum_c( conv_bias_c/2 + bias_c )
//
// Block = one (n, pd, 16x16 pooled hw-tile). Thread = one 2x2x2 pooled window.
// Weights are read with wave-uniform addresses -> s_load into SGPRs (no LDS, no VALU).
// Each 4x4 x-patch register load is reused for 2 output channels.

__global__ __launch_bounds__(256, 2) void conv_pool_kernel(
    const float* __restrict__ x, const float* __restrict__ wgt,
    float* __restrict__ ws)
{
  // input tile: [ci][4 d][34 h][36 w-padded] = 58,752 B
  __shared__ __align__(16) float xs[3*4*34*36];
  __shared__ float wsum[4];

  const int tid = threadIdx.x;
  const int tile = blockIdx.x;            // 0..3 : pht = tile>>1, pwt = tile&1
  const int pht = tile >> 1, pwt = tile & 1;
  const int pd  = blockIdx.y;             // 0..14
  const int n   = blockIdx.z;             // 0..31

  // ---- stage input tile (guarded halo; gh/gw >= 64 -> 0, never used by valid threads)
  const int H0 = 32*pht, W0 = 32*pwt, D0 = 2*pd;
  const float* xn = x + (size_t)n * (3*32*64*64);
  for (int i = tid; i < 3*4*34*34; i += 256) {
    int wq = i % 34; int t = i / 34;
    int hq = t % 34; t /= 34;
    int dq = t & 3;  int ci = t >> 2;
    int gh = H0 + hq, gw = W0 + wq;
    float v = 0.f;
    if (gh < 64 && gw < 64)
      v = xn[((ci*32 + (D0 + dq))*64 + gh)*64 + gw];
    xs[((ci*4 + dq)*34 + hq)*36 + wq] = v;
  }
  __syncthreads();

  const int ty = tid >> 4, tx = tid & 15;
  const int ph = pht*16 + ty, pw = pwt*16 + tx;
  const bool valid = (ph < 31) && (pw < 31);

  float S = 0.f;
  #pragma unroll 1
  for (int cg = 0; cg < 8; ++cg) {        // channel pair c0=2*cg, c1=2*cg+1
    float a0[8], a1[8];
    #pragma unroll
    for (int i = 0; i < 8; ++i) { a0[i] = 0.f; a1[i] = 0.f; }

    #pragma unroll
    for (int ci = 0; ci < 3; ++ci) {
      // wave-uniform weight reads -> SGPRs (s_load); literal offsets after unroll
      const float* wp = wgt + (size_t)(cg*6 + ci) * 27;   // (c0*3+ci)*27
      float w0[27], w1[27];
      #pragma unroll
      for (int k = 0; k < 27; ++k) { w0[k] = wp[k]; w1[k] = wp[81 + k]; }

      #pragma unroll
      for (int dq = 0; dq < 4; ++dq) {
        // 4x4 (h,w) register patch for this input-depth slice (8x ds_read_b64)
        float xr[16];
        const int xb = ((ci*4 + dq)*34 + 2*ty)*36 + 2*tx;
        #pragma unroll
        for (int r = 0; r < 4; ++r)
          #pragma unroll
          for (int q = 0; q < 4; ++q)
            xr[r*4 + q] = xs[xb + r*36 + q];

        #pragma unroll
        for (int dd = 0; dd < 2; ++dd) {
          const int kd = dq - dd;
          if (kd < 0 || kd > 2) continue;
          #pragma unroll
          for (int r = 0; r < 4; ++r) {
            #pragma unroll
            for (int dh = 0; dh < 2; ++dh) {
              const int kh = r - dh;
              if (kh < 0 || kh > 2) continue;
              #pragma unroll
              for (int kw = 0; kw < 3; ++kw) {
                #pragma unroll
                for (int dw = 0; dw < 2; ++dw) {
                  const float xv = xr[r*4 + kw + dw];
                  const float wk0 = w0[(kd*3 + kh)*3 + kw];
                  const float wk1 = w1[(kd*3 + kh)*3 + kw];
                  a0[dd*4 + dh*2 + dw] += wk0 * xv;
                  a1[dd*4 + dh*2 + dw] += wk1 * xv;
                }
              }
            }
          }
        }
      }
    }
    // maxpool over each 2x2x2 window, accumulate over both channels
    float m0 = fmaxf(fmaxf(fmaxf(a0[0], a0[1]), fmaxf(a0[2], a0[3])),
                     fmaxf(fmaxf(a0[4], a0[5]), fmaxf(a0[6], a0[7])));
    float m1 = fmaxf(fmaxf(fmaxf(a1[0], a1[1]), fmaxf(a1[2], a1[3])),
                     fmaxf(fmaxf(a1[4], a1[5]), fmaxf(a1[6], a1[7])));
    S += m0 + m1;
  }
  if (!valid) S = 0.f;

  // deterministic block reduction
  #pragma unroll
  for (int off = 32; off > 0; off >>= 1) S += __shfl_down(S, off, 64);
  if ((tid & 63) == 0) wsum[tid >> 6] = S;
  __syncthreads();
  if (tid == 0) {
    float tot = wsum[0] + wsum[1] + wsum[2] + wsum[3];
    ws[n*64 + (pd*4 + tile)] = tot;   // 60 slots per n, all written every launch
  }
}

__global__ void finalize_kernel(const float* __restrict__ ws,
                                const float* __restrict__ cb,
                                const float* __restrict__ bias,
                                float* __restrict__ out)
{
  int n = threadIdx.x;
  if (n >= 32) return;
  float tot = 0.f;
  #pragma unroll 1
  for (int s = 0; s < 60; ++s) tot += ws[n*64 + s];
  float C = 0.f;
  #pragma unroll 1
  for (int c = 0; c < 16; ++c) C += cb[c]*0.5f + bias[c];
  out[n] = tot * (1.0f/(2.0f*14415.0f)) + C;
}

extern "C" void kernel_launch(void* const* d_in, const int* in_sizes, int n_in,
                              void* d_out, int out_size, void* d_ws, size_t ws_size,
                              hipStream_t stream) {
  (void)in_sizes; (void)n_in; (void)out_size; (void)ws_size;
  const float* x    = (const float*)d_in[0];
  const float* wgt  = (const float*)d_in[1];
  const float* cb   = (const float*)d_in[2];
  const float* bias = (const float*)d_in[3];
  float* out = (float*)d_out;
  float* ws  = (float*)d_ws;     // needs 32*64*4 = 8 KB

  dim3 grid(4, 15, 32);          // (hw-tile, pd, n) = 1920 blocks
  conv_pool_kernel<<<grid, 256, 0, stream>>>(x, wgt, ws);
  finalize_kernel<<<1, 64, 0, stream>>>(ws, cb, bias, out);
}

// Round 3
// 155.332 us; speedup vs baseline: 1.5321x; 1.5241x over previous
//
#include <hip/hip_runtime.h>

// Fused Conv3d(3->16,k3,valid) + bias + /2 + MaxPool3d(2) + GlobalAvgPool + bias + channel-sum
// N=32, Cin=3, D=32,H=64,W=64 -> conv (30,62,62) -> pool (15,31,31) -> out (32)
//
// out[n] = (1/(2*14415)) * sum_{c,windows} max_window(conv_c) + sum_c( conv_bias_c/2 + bias_c )
//
// No LDS staging: each thread reads its own 4x4 patch from global (L1/L2 serve the
// 2x overlap between neighbor lanes), holds it in registers across 8 channels.
// Channels split across blocks (8 per block) -> acc fits 64 VGPRs, 4 waves/SIMD.

__global__ __launch_bounds__(256, 4) void conv_pool_kernel(
    const float* __restrict__ x, const float* __restrict__ wgt,
    float* __restrict__ ws)
{
  __shared__ float wsum[4];

  const int tid  = threadIdx.x;
  const int bx   = blockIdx.x;           // 0..7: tile = bx&3, channel-group g = bx>>2
  const int tile = bx & 3;
  const int g    = bx >> 2;              // channels g*8 .. g*8+7
  const int pht  = tile >> 1, pwt = tile & 1;
  const int pd   = blockIdx.y;           // 0..14
  const int n    = blockIdx.z;           // 0..31

  const int ty = tid >> 4, tx = tid & 15;
  const int ph = pht*16 + ty, pw = pwt*16 + tx;    // pooled coords, valid < 31
  const bool valid = (ph < 31) && (pw < 31);
  const int phc = (ph < 31) ? ph : 30;             // clamp: duplicates row 30, zeroed later
  const int pwc = (pw < 31) ? pw : 30;

  const float* xn = x + (size_t)n*(3*32*64*64) + (size_t)(2*pd)*(64*64);
  const int rowoff = (2*phc)*64 + 2*pwc;           // element offset within a d-slice

  float acc[8][8];
  #pragma unroll
  for (int c = 0; c < 8; ++c)
    #pragma unroll
    for (int i = 0; i < 8; ++i) acc[c][i] = 0.f;

  #pragma unroll 1
  for (int ci = 0; ci < 3; ++ci) {
    const float* xci = xn + (size_t)ci*(32*64*64);
    const float* wci = wgt + (size_t)(g*24 + ci)*27;   // ((g*8+c8)*3+ci)*27 = this + c8*81

    #pragma unroll
    for (int dq = 0; dq < 4; ++dq) {                   // input d-slice = 2*pd + dq
      // 4x4 (h,w) register patch, two 8B-aligned float2 loads per row
      float xr[16];
      const float* xrow = xci + dq*(64*64) + rowoff;
      #pragma unroll
      for (int r = 0; r < 4; ++r) {
        float2 lo = *reinterpret_cast<const float2*>(xrow + r*64);
        float2 hi = *reinterpret_cast<const float2*>(xrow + r*64 + 2);
        xr[r*4+0] = lo.x; xr[r*4+1] = lo.y; xr[r*4+2] = hi.x; xr[r*4+3] = hi.y;
      }

      #pragma unroll
      for (int c8 = 0; c8 < 8; ++c8) {
        const float* wp = wci + c8*81;                 // wave-uniform -> s_load
        #pragma unroll
        for (int dd = 0; dd < 2; ++dd) {
          const int kd = dq - dd;
          if (kd < 0 || kd > 2) continue;
          #pragma unroll
          for (int r = 0; r < 4; ++r) {
            #pragma unroll
            for (int dh = 0; dh < 2; ++dh) {
              const int kh = r - dh;
              if (kh < 0 || kh > 2) continue;
              #pragma unroll
              for (int kw = 0; kw < 3; ++kw) {
                const float wv = wp[(kd*3 + kh)*3 + kw];
                acc[c8][dd*4 + dh*2 + 0] += wv * xr[r*4 + kw + 0];
                acc[c8][dd*4 + dh*2 + 1] += wv * xr[r*4 + kw + 1];
              }
            }
          }
        }
      }
    }
  }

  // maxpool each 2x2x2 window, sum over this block's 8 channels
  float S = 0.f;
  #pragma unroll
  for (int c = 0; c < 8; ++c) {
    float m = fmaxf(fmaxf(fmaxf(acc[c][0], acc[c][1]), fmaxf(acc[c][2], acc[c][3])),
                    fmaxf(fmaxf(acc[c][4], acc[c][5]), fmaxf(acc[c][6], acc[c][7])));
    S += m;
  }
  if (!valid) S = 0.f;

  // deterministic block reduction
  #pragma unroll
  for (int off = 32; off > 0; off >>= 1) S += __shfl_down(S, off, 64);
  if ((tid & 63) == 0) wsum[tid >> 6] = S;
  __syncthreads();
  if (tid == 0) {
    float tot = wsum[0] + wsum[1] + wsum[2] + wsum[3];
    ws[n*128 + (pd*8 + bx)] = tot;     // 120 slots per n, all written every launch
  }
}

__global__ void finalize_kernel(const float* __restrict__ ws,
                                const float* __restrict__ cb,
                                const float* __restrict__ bias,
                                float* __restrict__ out)
{
  int n = threadIdx.x;
  if (n >= 32) return;
  float tot = 0.f;
  #pragma unroll 1
  for (int s = 0; s < 120; ++s) tot += ws[n*128 + s];
  float C = 0.f;
  #pragma unroll 1
  for (int c = 0; c < 16; ++c) C += cb[c]*0.5f + bias[c];
  out[n] = tot * (1.0f/(2.0f*14415.0f)) + C;
}

extern "C" void kernel_launch(void* const* d_in, const int* in_sizes, int n_in,
                              void* d_out, int out_size, void* d_ws, size_t ws_size,
                              hipStream_t stream) {
  (void)in_sizes; (void)n_in; (void)out_size; (void)ws_size;
  const float* x    = (const float*)d_in[0];
  const float* wgt  = (const float*)d_in[1];
  const float* cb   = (const float*)d_in[2];
  const float* bias = (const float*)d_in[3];
  float* out = (float*)d_out;
  float* ws  = (float*)d_ws;     // needs 32*128*4 = 16 KB

  dim3 grid(8, 15, 32);          // (hw-tile x channel-group, pd, n) = 3840 blocks
  conv_pool_kernel<<<grid, 256, 0, stream>>>(x, wgt, ws);
  finalize_kernel<<<1, 64, 0, stream>>>(ws, cb, bias, out);
}